// Round 3
// baseline (398.491 us; speedup 1.0000x reference)
//
#include <hip/hip_runtime.h>
#include <math.h>

#define BB 64
#define TT 8192
#define NTILES 8192      // 524288 positions / 64 per tile
#define MLP_GRID 1024    // 4 blocks/CU (LDS 17408*4, VGPR<=128), 8 iters even
#define EMA_GRID 512     // 64 b * 8 chunks of 1024 t

typedef short short8 __attribute__((ext_vector_type(8)));
typedef float f32x4 __attribute__((ext_vector_type(4)));

// f32 -> bf16 bits, RNE
__device__ __forceinline__ unsigned short f2bf(float x) {
    unsigned int u = __float_as_uint(x);
    u += 0x7fffu + ((u >> 16) & 1u);
    return (unsigned short)(u >> 16);
}

// two f32 -> packed bf16x2 (lo | hi<<16)
__device__ __forceinline__ unsigned int f2bf2(float lo, float hi) {
    return (unsigned int)f2bf(lo) | ((unsigned int)f2bf(hi) << 16);
}

__device__ __forceinline__ float fast_sigmoid(float z) {
    return __builtin_amdgcn_rcpf(1.0f + __expf(-z));
}

__device__ __forceinline__ float fast_gelu(float x) {
    // x * sigmoid(1.702x); abs err ~0.02 vs erf-gelu, budget is 2.1e4
    return x * fast_sigmoid(1.702f * x);
}

// ---------------------------------------------------------------------------
// Prep kernel: convert weights to bf16 layouts for L1-hot fragment loads.
//   w2bf[ch*128 + k] = bf16(W2[k][ch])            (128x128, 32 KB)
//   w1bf[ch*32 + k]  = bf16(W1[k][ch]) for k<20, b1[ch] at k==20, 0 pad
//                                                  (128x32,   8 KB)
// ---------------------------------------------------------------------------
__global__ __launch_bounds__(256) void prep_kernel(
    const float* __restrict__ W1, const float* __restrict__ b1,
    const float* __restrict__ W2,
    unsigned short* __restrict__ w1bf, unsigned short* __restrict__ w2bf)
{
    const int tid = threadIdx.x;
    const int bid = blockIdx.x;
    if (bid < 64) {
        int i  = bid * 256 + tid;          // 0..16383
        int ch = i >> 7, k = i & 127;
        w2bf[i] = f2bf(W2[k * 128 + ch]);
    } else {
        int i  = (bid - 64) * 256 + tid;   // 0..4095
        int ch = i >> 5, k = i & 31;
        float v = (k < 20) ? W1[k * 128 + ch] : ((k == 20) ? b1[ch] : 0.0f);
        w1bf[i] = f2bf(v);
    }
}

// ---------------------------------------------------------------------------
// EMA kernel (unchanged -- verified)
// ---------------------------------------------------------------------------
__global__ __launch_bounds__(256) void ema_kernel(
    const float* __restrict__ gaze, const float* __restrict__ logthr,
    const float* __restrict__ invT, float* __restrict__ qf, float* __restrict__ qs)
{
    __shared__ __align__(16) float sg[1280];
    const int tid = threadIdx.x;
    const int b   = blockIdx.x >> 3;
    const int t0  = (blockIdx.x & 7) << 10;
    const float thr = __expf(logthr[0]);
    const float sT  = invT[0];
    const float2* gz = (const float2*)gaze + (size_t)b * TT;

    #pragma unroll
    for (int it = 0; it < 5; ++it) {
        int i = tid + it * 256;
        int t = t0 - 252 + i;
        float val = 0.0f;
        if (t >= 0 && t < TT) {
            float vx = 0.0f, vy = 0.0f;
            if (t > 0) {
                float2 a = gz[t], p = gz[t - 1];
                vx = (a.x - p.x) * 240.0f;
                vy = (a.y - p.y) * 240.0f;
            }
            float speed = sqrtf(vx * vx + vy * vy);
            val = 1.0f / (1.0f + __expf(-sT * (speed - thr)));
        }
        sg[i] = val;
    }
    __syncthreads();

    const float4* sg4 = (const float4*)sg;
    float Sf = 0.0f, Ss = 0.0f;
    float wf = 0.16f;       // 0.2 * 0.8
    float ws = 0.0475f;     // 0.05 * 0.95
    for (int u = 62; u >= 0; --u) {
        float4 qv = sg4[tid + u];
        float hf = fmaf(0.8f,  fmaf(0.8f,  fmaf(0.8f,  qv.x, qv.y), qv.z), qv.w);
        Sf = fmaf(wf, hf, Sf);  wf *= 0.4096f;
        float hs = fmaf(0.95f, fmaf(0.95f, fmaf(0.95f, qv.x, qv.y), qv.z), qv.w);
        Ss = fmaf(ws, hs, Ss);  ws *= 0.81450625f;
    }
    float4 r = sg4[tid + 63];
    float g0v = r.x, g1v = r.y, g2v = r.z, g3v = r.w;

    float o0 = Sf + 0.2f * g0v;
    float o1 = fmaf(0.8f,   Sf, 0.2f * fmaf(0.8f, g0v, g1v));
    float o2 = fmaf(0.64f,  Sf, 0.2f * (g2v + 0.8f * g1v + 0.64f * g0v));
    float o3 = fmaf(0.512f, Sf, 0.2f * (g3v + 0.8f * g2v + 0.64f * g1v + 0.512f * g0v));

    float p0 = Ss + 0.05f * g0v;
    float p1 = fmaf(0.95f,     Ss, 0.05f * fmaf(0.95f, g0v, g1v));
    float p2 = fmaf(0.9025f,   Ss, 0.05f * (g2v + 0.95f * g1v + 0.9025f * g0v));
    float p3 = fmaf(0.857375f, Ss, 0.05f * (g3v + 0.95f * g2v + 0.9025f * g1v + 0.857375f * g0v));

    const size_t ob = (size_t)b * TT + t0 + 4 * tid;
    *(float4*)(qf + ob) = make_float4(o0, o1, o2, o3);
    *(float4*)(qs + ob) = make_float4(p0, p1, p2, p3);
}

// ---------------------------------------------------------------------------
// MLP kernel, L1-weights variant. vs round-1 (327 us base):
//  - W1/W2/b2 fragments loaded straight from global (bf16 via prep kernel).
//    W2bf = 32 KB -> L1-resident; loads are vmcnt-tracked, issue early,
//    independent of the h1 LDS roundtrip. No staging loop, NO barriers.
//  - LDS = sh1 only (17408 B/block) -> occupancy is VGPR-limited:
//    __launch_bounds__(256,4) targets 16 waves/CU (was 12). Lean body
//    (no 32-reg B1, no 32-reg bias residency) should fit 128 VGPRs.
//  - pointers re-pinned via empty asm each iteration so LICM cannot hoist
//    128 VGPRs of weight fragments out of the tile loop.
//  - MFMA layouts / sh1 layout / epilogues unchanged (verified).
// ---------------------------------------------------------------------------
__global__ __launch_bounds__(256, 4) void mlp_kernel(
    const float* __restrict__ gaze,
    const float* __restrict__ lwx, const float* __restrict__ phx,
    const float* __restrict__ lwy, const float* __restrict__ phy,
    const float* __restrict__ logthr, const float* __restrict__ invT,
    const unsigned short* __restrict__ w1bf, const unsigned short* __restrict__ w2bf,
    const float* __restrict__ b2,
    const float* __restrict__ qf, const float* __restrict__ qs,
    float* __restrict__ out)
{
    // per-wave h1 roundtrip area: [pos=16][ch stride 136] (2-way bank alias)
    __shared__ __align__(16) unsigned short sh1[4][16 * 136];   // 17408 B

    const int tid  = threadIdx.x;
    const int wave = tid >> 6;
    const int lane = tid & 63;
    const int c    = lane & 15;
    const int q    = lane >> 4;

    const float twopi = 6.283185307179586f;
    const float cwx0 = twopi * __expf(lwx[0]), cwx1 = twopi * __expf(lwx[1]);
    const float cwy0 = twopi * __expf(lwy[0]), cwy1 = twopi * __expf(lwy[1]);
    const float px0 = phx[0], px1 = phx[1], py0 = phy[0], py1 = phy[1];
    const float thr = __expf(logthr[0]), sT = invT[0];

    unsigned short* h1w = sh1[wave];
    const float2* gz = (const float2*)gaze;

    for (int tile = blockIdx.x; tile < NTILES; tile += MLP_GRID) {
        const int b   = tile >> 7;
        const int t0  = (tile & 127) << 6;
        const int t   = t0 + wave * 16 + c;
        const int idx = b * TT + t;

        // re-pin weight pointers: blocks LICM from hoisting frag loads
        unsigned long long a1 = (unsigned long long)w1bf;
        unsigned long long a2 = (unsigned long long)w2bf;
        unsigned long long a3 = (unsigned long long)b2;
        asm volatile("" : "+s"(a1), "+s"(a2), "+s"(a3));
        const unsigned short* w1p = (const unsigned short*)a1;
        const unsigned short* w2p = (const unsigned short*)a2;
        const float*          b2p = (const float*)a3;

        float2 g0 = gz[idx];
        float2 g1 = (t > 0) ? gz[idx - 1] : g0;
        float2 g2 = (t > 1) ? gz[idx - 2] : g1;
        float vx = (g0.x - g1.x) * 240.0f;
        float vy = (g0.y - g1.y) * 240.0f;
        float vpx = (g1.x - g2.x) * 240.0f;
        float vpy = (g1.y - g2.y) * 240.0f;
        float ax = (vx - vpx) * 240.0f;
        float ay = (vy - vpy) * 240.0f;
        float speed  = sqrtf(vx * vx + vy * vy);
        float inv_sp = __builtin_amdgcn_rcpf(speed + 1e-6f);

        float f[8] = {0.f, 0.f, 0.f, 0.f, 0.f, 0.f, 0.f, 0.f};
        if (q == 0) {
            __sincosf(fmaf(g0.x, cwx0, px0), &f[0], &f[2]);
            __sincosf(fmaf(g0.x, cwx1, px1), &f[1], &f[3]);
            __sincosf(fmaf(g0.y, cwy0, py0), &f[4], &f[6]);
            __sincosf(fmaf(g0.y, cwy1, py1), &f[5], &f[7]);
        } else if (q == 1) {
            f[0] = vx; f[1] = vy; f[2] = speed;
            f[3] = vx * inv_sp; f[4] = vy * inv_sp;
            f[5] = ax; f[6] = ay;
            f[7] = (vx * ax + vy * ay) * inv_sp;
        } else if (q == 2) {
            f[0] = (vx * ay - vy * ax) * inv_sp;
            f[1] = fast_sigmoid(sT * (speed - thr));
            f[2] = qf[idx];
            f[3] = qs[idx];
            f[4] = 1.0f;          // k=20: constant-1 feature carries b1
        } // q==3: zeros (k=24..31 zero-padded in w1bf)

        union { unsigned short u[8]; short8 v; } A1;
        #pragma unroll
        for (int k = 0; k < 8; ++k) A1.u[k] = f2bf(f[k]);

        // ---- layer 1 (transposed): D1^T[ch][pos] = mfma(W1^T, feats^T) ----
        // W1 frag from global (L1-hot, 8 KB total): row ch=16j+c, k=8q..8q+7
        #pragma unroll
        for (int j = 0; j < 8; ++j) {
            short8 B1j = *(const short8*)&w1p[(16 * j + c) * 32 + 8 * q];
            f32x4 acc = {0.f, 0.f, 0.f, 0.f};
            acc = __builtin_amdgcn_mfma_f32_16x16x32_bf16(B1j, A1.v, acc, 0, 0, 0);
            unsigned int lo = f2bf2(fast_gelu(acc[0]), fast_gelu(acc[1]));
            unsigned int hi = f2bf2(fast_gelu(acc[2]), fast_gelu(acc[3]));
            *(uint2*)&h1w[c * 136 + 16 * j + 4 * q] = make_uint2(lo, hi);
        }
        asm volatile("s_waitcnt lgkmcnt(0)" ::: "memory");  // wave-local RAW fence

        // ---- layer 2 B-frags (h1^T): lane reads h1[pos=c][k=32s+8q .. +8] ----
        short8 A2[4];
        #pragma unroll
        for (int s = 0; s < 4; ++s)
            A2[s] = *(const short8*)&h1w[c * 136 + 32 * s + 8 * q];

        // per-lane out base: position c, channel base 4q
        float* ob = out + (size_t)(b * TT + t0 + wave * 16 + c) * 128 + 4 * q;
        #pragma unroll
        for (int j = 0; j < 8; ++j) {
            f32x4 acc = *(const f32x4*)&b2p[16 * j + 4 * q];
            #pragma unroll
            for (int s = 0; s < 4; ++s) {
                // W2 frag from global (L1-hot, 32 KB): row ch=16j+c, k=32s+8q..
                short8 W2f = *(const short8*)&w2p[(16 * j + c) * 128 + 32 * s + 8 * q];
                acc = __builtin_amdgcn_mfma_f32_16x16x32_bf16(W2f, A2[s], acc, 0, 0, 0);
            }
            f32x4 o;
            #pragma unroll
            for (int r = 0; r < 4; ++r) o[r] = fast_gelu(acc[r]);
            __builtin_nontemporal_store(o, (f32x4*)(ob + 16 * j));
        }
    }
}

extern "C" void kernel_launch(void* const* d_in, const int* in_sizes, int n_in,
                              void* d_out, int out_size, void* d_ws, size_t ws_size,
                              hipStream_t stream)
{
    const float* gaze   = (const float*)d_in[0];
    const float* lwx    = (const float*)d_in[1];
    const float* phx    = (const float*)d_in[2];
    const float* lwy    = (const float*)d_in[3];
    const float* phy    = (const float*)d_in[4];
    const float* logthr = (const float*)d_in[5];
    const float* invT   = (const float*)d_in[6];
    const float* W1     = (const float*)d_in[7];
    const float* b1     = (const float*)d_in[8];
    const float* W2     = (const float*)d_in[9];
    const float* b2     = (const float*)d_in[10];
    float* out = (float*)d_out;

    float* qf = (float*)d_ws;                         // 2 MB
    float* qs = qf + BB * TT;                         // 2 MB
    unsigned short* w1bf = (unsigned short*)(qs + BB * TT);   // 8 KB
    unsigned short* w2bf = w1bf + 128 * 32;                   // 32 KB (ws >= 4.04 MB)

    prep_kernel<<<80, 256, 0, stream>>>(W1, b1, W2, w1bf, w2bf);
    ema_kernel<<<EMA_GRID, 256, 0, stream>>>(gaze, logthr, invT, qf, qs);
    mlp_kernel<<<MLP_GRID, 256, 0, stream>>>(gaze, lwx, phx, lwy, phy, logthr, invT,
                                             w1bf, w2bf, b2, qf, qs, out);
}

// Round 4
// 326.584 us; speedup vs baseline: 1.2202x; 1.2202x over previous
//
#include <hip/hip_runtime.h>
#include <math.h>

#define BB 64
#define TT 8192
#define NTILES 8192      // 524288 positions / 64 per tile
#define MLP_GRID 2048    // 4 tiles/block; robust to 3-or-4 blocks/CU residency
#define EMA_GRID 512     // 64 b * 8 chunks of 1024 t

typedef short short8 __attribute__((ext_vector_type(8)));
typedef float f32x4 __attribute__((ext_vector_type(4)));

// f32 -> bf16 bits, RNE
__device__ __forceinline__ unsigned short f2bf(float x) {
    unsigned int u = __float_as_uint(x);
    u += 0x7fffu + ((u >> 16) & 1u);
    return (unsigned short)(u >> 16);
}

// two f32 -> packed bf16x2 (lo | hi<<16)
__device__ __forceinline__ unsigned int f2bf2(float lo, float hi) {
    return (unsigned int)f2bf(lo) | ((unsigned int)f2bf(hi) << 16);
}

__device__ __forceinline__ float fast_sigmoid(float z) {
    return __builtin_amdgcn_rcpf(1.0f + __expf(-z));
}

__device__ __forceinline__ float fast_gelu(float x) {
    // x * sigmoid(1.702x); abs err ~0.02 vs erf-gelu, budget is 2.1e4
    return x * fast_sigmoid(1.702f * x);
}

// ---------------------------------------------------------------------------
// EMA kernel (unchanged -- verified)
// ---------------------------------------------------------------------------
__global__ __launch_bounds__(256) void ema_kernel(
    const float* __restrict__ gaze, const float* __restrict__ logthr,
    const float* __restrict__ invT, float* __restrict__ qf, float* __restrict__ qs)
{
    __shared__ __align__(16) float sg[1280];
    const int tid = threadIdx.x;
    const int b   = blockIdx.x >> 3;
    const int t0  = (blockIdx.x & 7) << 10;
    const float thr = __expf(logthr[0]);
    const float sT  = invT[0];
    const float2* gz = (const float2*)gaze + (size_t)b * TT;

    #pragma unroll
    for (int it = 0; it < 5; ++it) {
        int i = tid + it * 256;
        int t = t0 - 252 + i;
        float val = 0.0f;
        if (t >= 0 && t < TT) {
            float vx = 0.0f, vy = 0.0f;
            if (t > 0) {
                float2 a = gz[t], p = gz[t - 1];
                vx = (a.x - p.x) * 240.0f;
                vy = (a.y - p.y) * 240.0f;
            }
            float speed = sqrtf(vx * vx + vy * vy);
            val = 1.0f / (1.0f + __expf(-sT * (speed - thr)));
        }
        sg[i] = val;
    }
    __syncthreads();

    const float4* sg4 = (const float4*)sg;
    float Sf = 0.0f, Ss = 0.0f;
    float wf = 0.16f;       // 0.2 * 0.8
    float ws = 0.0475f;     // 0.05 * 0.95
    for (int u = 62; u >= 0; --u) {
        float4 qv = sg4[tid + u];
        float hf = fmaf(0.8f,  fmaf(0.8f,  fmaf(0.8f,  qv.x, qv.y), qv.z), qv.w);
        Sf = fmaf(wf, hf, Sf);  wf *= 0.4096f;
        float hs = fmaf(0.95f, fmaf(0.95f, fmaf(0.95f, qv.x, qv.y), qv.z), qv.w);
        Ss = fmaf(ws, hs, Ss);  ws *= 0.81450625f;
    }
    float4 r = sg4[tid + 63];
    float g0v = r.x, g1v = r.y, g2v = r.z, g3v = r.w;

    float o0 = Sf + 0.2f * g0v;
    float o1 = fmaf(0.8f,   Sf, 0.2f * fmaf(0.8f, g0v, g1v));
    float o2 = fmaf(0.64f,  Sf, 0.2f * (g2v + 0.8f * g1v + 0.64f * g0v));
    float o3 = fmaf(0.512f, Sf, 0.2f * (g3v + 0.8f * g2v + 0.64f * g1v + 0.512f * g0v));

    float p0 = Ss + 0.05f * g0v;
    float p1 = fmaf(0.95f,     Ss, 0.05f * fmaf(0.95f, g0v, g1v));
    float p2 = fmaf(0.9025f,   Ss, 0.05f * (g2v + 0.95f * g1v + 0.9025f * g0v));
    float p3 = fmaf(0.857375f, Ss, 0.05f * (g3v + 0.95f * g2v + 0.9025f * g1v + 0.857375f * g0v));

    const size_t ob = (size_t)b * TT + t0 + 4 * tid;
    *(float4*)(qf + ob) = make_float4(o0, o1, o2, o3);
    *(float4*)(qs + ob) = make_float4(p0, p1, p2, p3);
}

// ---------------------------------------------------------------------------
// MLP kernel, sigma-permuted channels -> NO h1 LDS roundtrip. vs r1 (327us):
//  - W1 MFMA-row i of block j computes channel sigma(j,i) =
//    32*(j&3) + 8*(i>>2) + 4*(j>>2) + (i&3). With the (verified) D-layout
//    (lane (c,q) holds rows 4q+r), lane (c,q) then holds EXACTLY the true
//    channels {32s+8q+u} that its layer-2 B-fragment A2[s] needs:
//      A2[s] = pack8(gelu(acc[s][0..3]), gelu(acc[s+4][0..3]))  -- lane-local.
//    b1 folds per-row (k=20 constant-1 feature), so it permutes for free.
//    sW2 indexing and output layout are UNCHANGED (lanes land on true ch IDs).
//  - deletes per tile: 8 ds_write_b64 + 4 ds_read_b128 + lgkmcnt(0) drain.
//  - LDS = sW2 34816 + sb2 512 = 35328 -> 4 blocks/CU; launch_bounds(256,4).
//  - bias2 in LDS (broadcast b128 reads), not 32 VGPRs, to fit 128 regs.
// ---------------------------------------------------------------------------
__global__ __launch_bounds__(256, 4) void mlp_kernel(
    const float* __restrict__ gaze,
    const float* __restrict__ lwx, const float* __restrict__ phx,
    const float* __restrict__ lwy, const float* __restrict__ phy,
    const float* __restrict__ logthr, const float* __restrict__ invT,
    const float* __restrict__ W1, const float* __restrict__ b1,
    const float* __restrict__ W2, const float* __restrict__ b2,
    const float* __restrict__ qf, const float* __restrict__ qs,
    float* __restrict__ out)
{
    // W2^T[n][k], bf16, row stride 136 (16B-aligned rows; <=2-way aliasing)
    __shared__ __align__(16) unsigned short sW2[128 * 136];     // 34816 B
    __shared__ __align__(16) float sb2[128];                    // 512 B

    const int tid  = threadIdx.x;
    const int lane = tid & 63;
    const int wave = tid >> 6;
    const int c    = lane & 15;
    const int q    = lane >> 4;

    // ---- stage W2^T bf16 (one-time; coalesced over n) ----
    #pragma unroll
    for (int it = 0; it < 32; ++it) {
        int i  = tid + it * 256;
        int n  = i & 127;
        int kp = i >> 7;
        unsigned short lo = f2bf(W2[(2 * kp) * 128 + n]);
        unsigned short hi = f2bf(W2[(2 * kp + 1) * 128 + n]);
        *(unsigned int*)&sW2[n * 136 + 2 * kp] = ((unsigned int)hi << 16) | lo;
    }
    if (tid < 128) sb2[tid] = b2[tid];

    // ---- W1^T frags, sigma-permuted rows: B1[j] lane (c,q) holds
    //      W1^T[ch=sigma(j,c)][k=8q..8q+7]; k==20 carries b1[ch] ----
    short8 B1[8];
    #pragma unroll
    for (int j = 0; j < 8; ++j) {
        const int ch = 32 * (j & 3) + 8 * (c >> 2) + 4 * (j >> 2) + (c & 3);
        union { unsigned short u[8]; short8 v; } tmp;
        #pragma unroll
        for (int u = 0; u < 8; ++u) {
            int k = 8 * q + u;
            float w = 0.0f;
            if (k < 20)       w = W1[k * 128 + ch];
            else if (k == 20) w = b1[ch];
            tmp.u[u] = (k <= 20) ? f2bf(w) : (unsigned short)0;
        }
        B1[j] = tmp.v;
    }

    const float twopi = 6.283185307179586f;
    const float cwx0 = twopi * __expf(lwx[0]), cwx1 = twopi * __expf(lwx[1]);
    const float cwy0 = twopi * __expf(lwy[0]), cwy1 = twopi * __expf(lwy[1]);
    const float px0 = phx[0], px1 = phx[1], py0 = phy[0], py1 = phy[1];
    const float thr = __expf(logthr[0]), sT = invT[0];

    __syncthreads();   // sW2/sb2 visible; no barriers needed after this

    const float2* gz = (const float2*)gaze;

    for (int tile = blockIdx.x; tile < NTILES; tile += MLP_GRID) {
        const int b   = tile >> 7;
        const int t0  = (tile & 127) << 6;
        const int t   = t0 + wave * 16 + c;
        const int idx = b * TT + t;

        float2 g0 = gz[idx];
        float2 g1 = (t > 0) ? gz[idx - 1] : g0;
        float2 g2 = (t > 1) ? gz[idx - 2] : g1;
        float vx = (g0.x - g1.x) * 240.0f;
        float vy = (g0.y - g1.y) * 240.0f;
        float vpx = (g1.x - g2.x) * 240.0f;
        float vpy = (g1.y - g2.y) * 240.0f;
        float ax = (vx - vpx) * 240.0f;
        float ay = (vy - vpy) * 240.0f;
        float speed  = sqrtf(vx * vx + vy * vy);
        float inv_sp = __builtin_amdgcn_rcpf(speed + 1e-6f);

        float f[8] = {0.f, 0.f, 0.f, 0.f, 0.f, 0.f, 0.f, 0.f};
        if (q == 0) {
            __sincosf(fmaf(g0.x, cwx0, px0), &f[0], &f[2]);
            __sincosf(fmaf(g0.x, cwx1, px1), &f[1], &f[3]);
            __sincosf(fmaf(g0.y, cwy0, py0), &f[4], &f[6]);
            __sincosf(fmaf(g0.y, cwy1, py1), &f[5], &f[7]);
        } else if (q == 1) {
            f[0] = vx; f[1] = vy; f[2] = speed;
            f[3] = vx * inv_sp; f[4] = vy * inv_sp;
            f[5] = ax; f[6] = ay;
            f[7] = (vx * ax + vy * ay) * inv_sp;
        } else if (q == 2) {
            f[0] = (vx * ay - vy * ax) * inv_sp;
            f[1] = fast_sigmoid(sT * (speed - thr));
            f[2] = qf[idx];
            f[3] = qs[idx];
            f[4] = 1.0f;          // k=20: constant-1 feature carries b1
        } // q==3: zeros (K padding)

        union { unsigned short u[8]; short8 v; } A1;
        #pragma unroll
        for (int k = 0; k < 8; ++k) A1.u[k] = f2bf(f[k]);

        // ---- layer 1: 8 MFMAs, accumulators stay in registers ----
        f32x4 acc1[8];
        #pragma unroll
        for (int j = 0; j < 8; ++j) {
            f32x4 z = {0.f, 0.f, 0.f, 0.f};
            acc1[j] = __builtin_amdgcn_mfma_f32_16x16x32_bf16(B1[j], A1.v, z, 0, 0, 0);
        }

        // ---- lane-local repack: A2[s] = channels {32s+8q+u}, pos=c ----
        short8 A2[4];
        #pragma unroll
        for (int s = 0; s < 4; ++s) {
            union { unsigned int w[4]; short8 v; } t2;
            t2.w[0] = f2bf2(fast_gelu(acc1[s][0]),     fast_gelu(acc1[s][1]));
            t2.w[1] = f2bf2(fast_gelu(acc1[s][2]),     fast_gelu(acc1[s][3]));
            t2.w[2] = f2bf2(fast_gelu(acc1[s + 4][0]), fast_gelu(acc1[s + 4][1]));
            t2.w[3] = f2bf2(fast_gelu(acc1[s + 4][2]), fast_gelu(acc1[s + 4][3]));
            A2[s] = t2.v;
        }

        // ---- layer 2: per-lane out base pos=c, channel base 4q ----
        float* ob = out + (size_t)(b * TT + t0 + wave * 16 + c) * 128 + 4 * q;
        #pragma unroll
        for (int j = 0; j < 8; ++j) {
            f32x4 acc = *(const f32x4*)&sb2[16 * j + 4 * q];
            #pragma unroll
            for (int s = 0; s < 4; ++s) {
                short8 W2f = *(const short8*)&sW2[(16 * j + c) * 136 + 32 * s + 8 * q];
                acc = __builtin_amdgcn_mfma_f32_16x16x32_bf16(W2f, A2[s], acc, 0, 0, 0);
            }
            f32x4 o;
            #pragma unroll
            for (int r = 0; r < 4; ++r) o[r] = fast_gelu(acc[r]);
            __builtin_nontemporal_store(o, (f32x4*)(ob + 16 * j));
        }
    }
}

extern "C" void kernel_launch(void* const* d_in, const int* in_sizes, int n_in,
                              void* d_out, int out_size, void* d_ws, size_t ws_size,
                              hipStream_t stream)
{
    const float* gaze   = (const float*)d_in[0];
    const float* lwx    = (const float*)d_in[1];
    const float* phx    = (const float*)d_in[2];
    const float* lwy    = (const float*)d_in[3];
    const float* phy    = (const float*)d_in[4];
    const float* logthr = (const float*)d_in[5];
    const float* invT   = (const float*)d_in[6];
    const float* W1     = (const float*)d_in[7];
    const float* b1     = (const float*)d_in[8];
    const float* W2     = (const float*)d_in[9];
    const float* b2     = (const float*)d_in[10];
    float* out = (float*)d_out;

    float* qf = (float*)d_ws;            // 2 MB
    float* qs = qf + BB * TT;            // 2 MB (ws_size >= 4 MB)

    ema_kernel<<<EMA_GRID, 256, 0, stream>>>(gaze, logthr, invT, qf, qs);
    mlp_kernel<<<MLP_GRID, 256, 0, stream>>>(gaze, lwx, phx, lwy, phy, logthr, invT,
                                             W1, b1, W2, b2, qf, qs, out);
}

// Round 5
// 310.776 us; speedup vs baseline: 1.2822x; 1.0509x over previous
//
#include <hip/hip_runtime.h>
#include <math.h>

#define BB 64
#define TT 8192
#define NTILES 8192      // 524288 positions / 64 per tile
#define MLP_GRID 2048    // 4 tiles/block; robust to 3-or-4 blocks/CU residency
#define EMA_GRID 512     // 64 b * 8 chunks of 1024 t

typedef short short8 __attribute__((ext_vector_type(8)));
typedef float f32x4 __attribute__((ext_vector_type(4)));

// f32 -> bf16 bits, RNE
__device__ __forceinline__ unsigned short f2bf(float x) {
    unsigned int u = __float_as_uint(x);
    u += 0x7fffu + ((u >> 16) & 1u);
    return (unsigned short)(u >> 16);
}

// two f32 -> packed bf16x2 (lo | hi<<16)
__device__ __forceinline__ unsigned int f2bf2(float lo, float hi) {
    return (unsigned int)f2bf(lo) | ((unsigned int)f2bf(hi) << 16);
}

__device__ __forceinline__ float fast_sigmoid(float z) {
    return __builtin_amdgcn_rcpf(1.0f + __expf(-z));
}

__device__ __forceinline__ float fast_gelu(float x) {
    // x * sigmoid(1.702x); abs err ~0.02 vs erf-gelu, budget is 2.1e4
    return x * fast_sigmoid(1.702f * x);
}

// ---------------------------------------------------------------------------
// EMA kernel (unchanged -- verified)
// ---------------------------------------------------------------------------
__global__ __launch_bounds__(256) void ema_kernel(
    const float* __restrict__ gaze, const float* __restrict__ logthr,
    const float* __restrict__ invT, float* __restrict__ qf, float* __restrict__ qs)
{
    __shared__ __align__(16) float sg[1280];
    const int tid = threadIdx.x;
    const int b   = blockIdx.x >> 3;
    const int t0  = (blockIdx.x & 7) << 10;
    const float thr = __expf(logthr[0]);
    const float sT  = invT[0];
    const float2* gz = (const float2*)gaze + (size_t)b * TT;

    #pragma unroll
    for (int it = 0; it < 5; ++it) {
        int i = tid + it * 256;
        int t = t0 - 252 + i;
        float val = 0.0f;
        if (t >= 0 && t < TT) {
            float vx = 0.0f, vy = 0.0f;
            if (t > 0) {
                float2 a = gz[t], p = gz[t - 1];
                vx = (a.x - p.x) * 240.0f;
                vy = (a.y - p.y) * 240.0f;
            }
            float speed = sqrtf(vx * vx + vy * vy);
            val = 1.0f / (1.0f + __expf(-sT * (speed - thr)));
        }
        sg[i] = val;
    }
    __syncthreads();

    const float4* sg4 = (const float4*)sg;
    float Sf = 0.0f, Ss = 0.0f;
    float wf = 0.16f;       // 0.2 * 0.8
    float ws = 0.0475f;     // 0.05 * 0.95
    for (int u = 62; u >= 0; --u) {
        float4 qv = sg4[tid + u];
        float hf = fmaf(0.8f,  fmaf(0.8f,  fmaf(0.8f,  qv.x, qv.y), qv.z), qv.w);
        Sf = fmaf(wf, hf, Sf);  wf *= 0.4096f;
        float hs = fmaf(0.95f, fmaf(0.95f, fmaf(0.95f, qv.x, qv.y), qv.z), qv.w);
        Ss = fmaf(ws, hs, Ss);  ws *= 0.81450625f;
    }
    float4 r = sg4[tid + 63];
    float g0v = r.x, g1v = r.y, g2v = r.z, g3v = r.w;

    float o0 = Sf + 0.2f * g0v;
    float o1 = fmaf(0.8f,   Sf, 0.2f * fmaf(0.8f, g0v, g1v));
    float o2 = fmaf(0.64f,  Sf, 0.2f * (g2v + 0.8f * g1v + 0.64f * g0v));
    float o3 = fmaf(0.512f, Sf, 0.2f * (g3v + 0.8f * g2v + 0.64f * g1v + 0.512f * g0v));

    float p0 = Ss + 0.05f * g0v;
    float p1 = fmaf(0.95f,     Ss, 0.05f * fmaf(0.95f, g0v, g1v));
    float p2 = fmaf(0.9025f,   Ss, 0.05f * (g2v + 0.95f * g1v + 0.9025f * g0v));
    float p3 = fmaf(0.857375f, Ss, 0.05f * (g3v + 0.95f * g2v + 0.9025f * g1v + 0.857375f * g0v));

    const size_t ob = (size_t)b * TT + t0 + 4 * tid;
    *(float4*)(qf + ob) = make_float4(o0, o1, o2, o3);
    *(float4*)(qs + ob) = make_float4(p0, p1, p2, p3);
}

// ---------------------------------------------------------------------------
// MLP kernel. vs r4 (326.6us): ONE change -- output stores go through L2
// (nontemporal hint removed). The wave store pattern is 16 x 64B scattered
// chunks per instruction; NT bypasses L2 write-merge so these hit HBM as
// 64B partial-line writes (~50% write efficiency). Cached stores let L2
// merge the +64B-apart j/j+1 chunks into full 128B lines.
// Everything else identical to r4 (sigma-permuted channels, no h1 LDS
// roundtrip, 4 blocks/CU).
// ---------------------------------------------------------------------------
__global__ __launch_bounds__(256, 4) void mlp_kernel(
    const float* __restrict__ gaze,
    const float* __restrict__ lwx, const float* __restrict__ phx,
    const float* __restrict__ lwy, const float* __restrict__ phy,
    const float* __restrict__ logthr, const float* __restrict__ invT,
    const float* __restrict__ W1, const float* __restrict__ b1,
    const float* __restrict__ W2, const float* __restrict__ b2,
    const float* __restrict__ qf, const float* __restrict__ qs,
    float* __restrict__ out)
{
    // W2^T[n][k], bf16, row stride 136 (16B-aligned rows; <=2-way aliasing)
    __shared__ __align__(16) unsigned short sW2[128 * 136];     // 34816 B
    __shared__ __align__(16) float sb2[128];                    // 512 B

    const int tid  = threadIdx.x;
    const int lane = tid & 63;
    const int wave = tid >> 6;
    const int c    = lane & 15;
    const int q    = lane >> 4;

    // ---- stage W2^T bf16 (one-time; coalesced over n) ----
    #pragma unroll
    for (int it = 0; it < 32; ++it) {
        int i  = tid + it * 256;
        int n  = i & 127;
        int kp = i >> 7;
        unsigned short lo = f2bf(W2[(2 * kp) * 128 + n]);
        unsigned short hi = f2bf(W2[(2 * kp + 1) * 128 + n]);
        *(unsigned int*)&sW2[n * 136 + 2 * kp] = ((unsigned int)hi << 16) | lo;
    }
    if (tid < 128) sb2[tid] = b2[tid];

    // ---- W1^T frags, sigma-permuted rows: B1[j] lane (c,q) holds
    //      W1^T[ch=sigma(j,c)][k=8q..8q+7]; k==20 carries b1[ch] ----
    short8 B1[8];
    #pragma unroll
    for (int j = 0; j < 8; ++j) {
        const int ch = 32 * (j & 3) + 8 * (c >> 2) + 4 * (j >> 2) + (c & 3);
        union { unsigned short u[8]; short8 v; } tmp;
        #pragma unroll
        for (int u = 0; u < 8; ++u) {
            int k = 8 * q + u;
            float w = 0.0f;
            if (k < 20)       w = W1[k * 128 + ch];
            else if (k == 20) w = b1[ch];
            tmp.u[u] = (k <= 20) ? f2bf(w) : (unsigned short)0;
        }
        B1[j] = tmp.v;
    }

    const float twopi = 6.283185307179586f;
    const float cwx0 = twopi * __expf(lwx[0]), cwx1 = twopi * __expf(lwx[1]);
    const float cwy0 = twopi * __expf(lwy[0]), cwy1 = twopi * __expf(lwy[1]);
    const float px0 = phx[0], px1 = phx[1], py0 = phy[0], py1 = phy[1];
    const float thr = __expf(logthr[0]), sT = invT[0];

    __syncthreads();   // sW2/sb2 visible; no barriers needed after this

    const float2* gz = (const float2*)gaze;

    for (int tile = blockIdx.x; tile < NTILES; tile += MLP_GRID) {
        const int b   = tile >> 7;
        const int t0  = (tile & 127) << 6;
        const int t   = t0 + wave * 16 + c;
        const int idx = b * TT + t;

        float2 g0 = gz[idx];
        float2 g1 = (t > 0) ? gz[idx - 1] : g0;
        float2 g2 = (t > 1) ? gz[idx - 2] : g1;
        float vx = (g0.x - g1.x) * 240.0f;
        float vy = (g0.y - g1.y) * 240.0f;
        float vpx = (g1.x - g2.x) * 240.0f;
        float vpy = (g1.y - g2.y) * 240.0f;
        float ax = (vx - vpx) * 240.0f;
        float ay = (vy - vpy) * 240.0f;
        float speed  = sqrtf(vx * vx + vy * vy);
        float inv_sp = __builtin_amdgcn_rcpf(speed + 1e-6f);

        float f[8] = {0.f, 0.f, 0.f, 0.f, 0.f, 0.f, 0.f, 0.f};
        if (q == 0) {
            __sincosf(fmaf(g0.x, cwx0, px0), &f[0], &f[2]);
            __sincosf(fmaf(g0.x, cwx1, px1), &f[1], &f[3]);
            __sincosf(fmaf(g0.y, cwy0, py0), &f[4], &f[6]);
            __sincosf(fmaf(g0.y, cwy1, py1), &f[5], &f[7]);
        } else if (q == 1) {
            f[0] = vx; f[1] = vy; f[2] = speed;
            f[3] = vx * inv_sp; f[4] = vy * inv_sp;
            f[5] = ax; f[6] = ay;
            f[7] = (vx * ax + vy * ay) * inv_sp;
        } else if (q == 2) {
            f[0] = (vx * ay - vy * ax) * inv_sp;
            f[1] = fast_sigmoid(sT * (speed - thr));
            f[2] = qf[idx];
            f[3] = qs[idx];
            f[4] = 1.0f;          // k=20: constant-1 feature carries b1
        } // q==3: zeros (K padding)

        union { unsigned short u[8]; short8 v; } A1;
        #pragma unroll
        for (int k = 0; k < 8; ++k) A1.u[k] = f2bf(f[k]);

        // ---- layer 1: 8 MFMAs, accumulators stay in registers ----
        f32x4 acc1[8];
        #pragma unroll
        for (int j = 0; j < 8; ++j) {
            f32x4 z = {0.f, 0.f, 0.f, 0.f};
            acc1[j] = __builtin_amdgcn_mfma_f32_16x16x32_bf16(B1[j], A1.v, z, 0, 0, 0);
        }

        // ---- lane-local repack: A2[s] = channels {32s+8q+u}, pos=c ----
        short8 A2[4];
        #pragma unroll
        for (int s = 0; s < 4; ++s) {
            union { unsigned int w[4]; short8 v; } t2;
            t2.w[0] = f2bf2(fast_gelu(acc1[s][0]),     fast_gelu(acc1[s][1]));
            t2.w[1] = f2bf2(fast_gelu(acc1[s][2]),     fast_gelu(acc1[s][3]));
            t2.w[2] = f2bf2(fast_gelu(acc1[s + 4][0]), fast_gelu(acc1[s + 4][1]));
            t2.w[3] = f2bf2(fast_gelu(acc1[s + 4][2]), fast_gelu(acc1[s + 4][3]));
            A2[s] = t2.v;
        }

        // ---- layer 2: per-lane out base pos=c, channel base 4q ----
        float* ob = out + (size_t)(b * TT + t0 + wave * 16 + c) * 128 + 4 * q;
        #pragma unroll
        for (int j = 0; j < 8; ++j) {
            f32x4 acc = *(const f32x4*)&sb2[16 * j + 4 * q];
            #pragma unroll
            for (int s = 0; s < 4; ++s) {
                short8 W2f = *(const short8*)&sW2[(16 * j + c) * 136 + 32 * s + 8 * q];
                acc = __builtin_amdgcn_mfma_f32_16x16x32_bf16(W2f, A2[s], acc, 0, 0, 0);
            }
            f32x4 o;
            #pragma unroll
            for (int r = 0; r < 4; ++r) o[r] = fast_gelu(acc[r]);
            *(f32x4*)(ob + 16 * j) = o;   // cached store: L2 merges into full lines
        }
    }
}

extern "C" void kernel_launch(void* const* d_in, const int* in_sizes, int n_in,
                              void* d_out, int out_size, void* d_ws, size_t ws_size,
                              hipStream_t stream)
{
    const float* gaze   = (const float*)d_in[0];
    const float* lwx    = (const float*)d_in[1];
    const float* phx    = (const float*)d_in[2];
    const float* lwy    = (const float*)d_in[3];
    const float* phy    = (const float*)d_in[4];
    const float* logthr = (const float*)d_in[5];
    const float* invT   = (const float*)d_in[6];
    const float* W1     = (const float*)d_in[7];
    const float* b1     = (const float*)d_in[8];
    const float* W2     = (const float*)d_in[9];
    const float* b2     = (const float*)d_in[10];
    float* out = (float*)d_out;

    float* qf = (float*)d_ws;            // 2 MB
    float* qs = qf + BB * TT;            // 2 MB (ws_size >= 4 MB)

    ema_kernel<<<EMA_GRID, 256, 0, stream>>>(gaze, logthr, invT, qf, qs);
    mlp_kernel<<<MLP_GRID, 256, 0, stream>>>(gaze, lwx, phx, lwy, phy, logthr, invT,
                                             W1, b1, W2, b2, qf, qs, out);
}